// Round 6
// baseline (311.037 us; speedup 1.0000x reference)
//
#include <hip/hip_runtime.h>

#define N_NODES 50000
#define N_EDGES 800000
#define CH 128
#define NOUT 10
#define NUM_GRAPHS 128
#define GR 64                                              // rows per block
#define GEMM_BLOCKS ((N_NODES + GR - 1) / GR)              // 782
#define FILL_SEGS 200
#define FILL_CHUNK (N_EDGES / FILL_SEGS)                   // 4000 (16KB: int4-aligned)
#define FILL_BLOCKS (FILL_SEGS * 8)                        // 1600
#define DST_RANGE (N_NODES / 8)                            // 6250
#define DEG_CAP 64

typedef __attribute__((ext_vector_type(8))) short bf16x8;
typedef __attribute__((ext_vector_type(4))) float f32x4;

union FragU { uint4 u; bf16x8 s; };

__device__ __forceinline__ unsigned pack_bf16(float a, float b) {
    unsigned ua = __float_as_uint(a), ub = __float_as_uint(b);
    ua += 0x7fffu + ((ua >> 16) & 1u);
    ub += 0x7fffu + ((ub >> 16) & 1u);
    return (ua >> 16) | (ub & 0xffff0000u);
}

__device__ __forceinline__ unsigned short cvt_bf16(float v) {
    unsigned u = __float_as_uint(v);
    u += 0x7fffu + ((u >> 16) & 1u);
    return (unsigned short)(u >> 16);
}

// ===== K0: W pre-convert + zero fill_pos + zero psum =====
// Wb1: GEMM layout — uint4 index kg*128 + n holds fragment (k-group kg, col n).
// Wb2: FUSED layout — fragment (kg,n) at uint4 index
//      (kg>>2)*512 + (n&7)*64 + (kg&3)*16 + (n>>3)  -> B-loads linear in lane.
__global__ __launch_bounds__(256) void k_prep(const float* __restrict__ W1,
                                              const float* __restrict__ W2,
                                              unsigned short* __restrict__ Wb1,
                                              unsigned short* __restrict__ Wb2,
                                              int* __restrict__ fill_pos,
                                              float* __restrict__ psum) {
    if (blockIdx.x == 0) {
        for (int i = threadIdx.x; i < CH * CH; i += 256) {
            int k = i >> 7, n = i & 127;
            Wb1[((((k >> 3) << 7) + n) << 3) + (k & 7)] = cvt_bf16(W1[i]);
        }
    } else if (blockIdx.x == 1) {
        for (int i = threadIdx.x; i < CH * CH; i += 256) {
            int k = i >> 7, n = i & 127;
            int kg = k >> 3, ki = k & 7;
            int p = ((kg >> 2) << 9) + ((n & 7) << 6) + ((kg & 3) << 4) + (n >> 3);
            Wb2[(p << 3) + ki] = cvt_bf16(W2[i]);
        }
    } else if (blockIdx.x < 198) {
        int idx = (blockIdx.x - 2) * 256 + threadIdx.x;
        if (idx < N_NODES) fill_pos[idx] = 0;
    } else {
        psum[(blockIdx.x - 198) * 256 + threadIdx.x] = 0.f;
    }
}

// ===== conv1 MFMA GEMM body (unscaled): x fp32 -> tb bf16 =====
__device__ __forceinline__ void gemm_body(const float* __restrict__ X,
                                          const unsigned short* __restrict__ Wb,
                                          unsigned short* __restrict__ Yb,
                                          int bid) {
    const int tid = threadIdx.x;
    const int w = tid >> 6;
    const int lane = tid & 63;
    const int m = lane & 15;
    const int quad = lane >> 4;
    const int row0 = bid * GR + w * 16;

    int row_a = row0 + m;
    if (row_a > N_NODES - 1) row_a = N_NODES - 1;

    const float4* Xr = (const float4*)(X + (size_t)row_a * CH) + quad * 2;
    float4 a[8];
    #pragma unroll
    for (int ks = 0; ks < 4; ++ks) {
        a[ks * 2]     = Xr[ks * 8];
        a[ks * 2 + 1] = Xr[ks * 8 + 1];
    }
    FragU af[4];
    #pragma unroll
    for (int ks = 0; ks < 4; ++ks) {
        af[ks].u.x = pack_bf16(a[ks * 2].x, a[ks * 2].y);
        af[ks].u.y = pack_bf16(a[ks * 2].z, a[ks * 2].w);
        af[ks].u.z = pack_bf16(a[ks * 2 + 1].x, a[ks * 2 + 1].y);
        af[ks].u.w = pack_bf16(a[ks * 2 + 1].z, a[ks * 2 + 1].w);
    }

    f32x4 acc[8];
    #pragma unroll
    for (int ct = 0; ct < 8; ++ct) acc[ct] = (f32x4){0.f, 0.f, 0.f, 0.f};

    const uint4* Wq = (const uint4*)Wb;
    #pragma unroll
    for (int ks = 0; ks < 4; ++ks) {
        const int kg = ks * 4 + quad;
        #pragma unroll
        for (int ct = 0; ct < 8; ++ct) {
            FragU bfu;
            bfu.u = Wq[kg * 128 + m * 8 + ct];     // col n = m*8+ct rides lane m
            acc[ct] = __builtin_amdgcn_mfma_f32_16x16x32_bf16(af[ks].s, bfu.s, acc[ct], 0, 0, 0);
        }
    }

    #pragma unroll
    for (int r = 0; r < 4; ++r) {
        int row = row0 + quad * 4 + r;
        if (row < N_NODES) {
            uint4 o;
            o.x = pack_bf16(acc[0][r], acc[1][r]);
            o.y = pack_bf16(acc[2][r], acc[3][r]);
            o.z = pack_bf16(acc[4][r], acc[5][r]);
            o.w = pack_bf16(acc[6][r], acc[7][r]);
            *(uint4*)(Yb + (size_t)row * CH + m * 8) = o;   // 16B coalesced
        }
    }
}

// ===== K1: conv1 GEMM first, then XCD bucket-fill (best measured config) =====
__global__ __launch_bounds__(256) void k_gemm_fill(const float* __restrict__ X,
                                                   const unsigned short* __restrict__ Wb,
                                                   unsigned short* __restrict__ Yb,
                                                   const int* __restrict__ src,
                                                   const int* __restrict__ dst,
                                                   int* __restrict__ fill_pos,
                                                   int* __restrict__ csr_src) {
    if (blockIdx.x < GEMM_BLOCKS) {
        gemm_body(X, Wb, Yb, blockIdx.x);
    } else {
        const int b = blockIdx.x - GEMM_BLOCKS;
        const int rng = b & 7;                 // maps to a fixed XCD (L2 locality)
        const int seg = b >> 3;
        const int lo = rng * DST_RANGE, hi = lo + DST_RANGE;
        const int base = seg * FILL_CHUNK;
        for (int it = threadIdx.x * 4; it < FILL_CHUNK; it += 1024) {
            int e = base + it;
            int4 d4 = *(const int4*)(dst + e);   // 16B-aligned
            int4 s4 = *(const int4*)(src + e);   // unconditional src
            #pragma unroll
            for (int k = 0; k < 4; ++k) {
                int d = (&d4.x)[k];
                if (d >= lo && d < hi) {
                    int slot = atomicAdd(&fill_pos[d], 1);
                    if (slot < DEG_CAP) csr_src[(d << 6) + slot] = (&s4.x)[k];
                }
            }
        }
    }
}

__device__ __forceinline__ void acc_row(float (&x)[8], uint4 q, float w) {
    #pragma unroll
    for (int t = 0; t < 4; ++t) {
        unsigned r = ((const unsigned*)&q)[t];
        x[2 * t]     = fmaf(w, __uint_as_float(r << 16), x[2 * t]);
        x[2 * t + 1] = fmaf(w, __uint_as_float(r & 0xffff0000u), x[2 * t + 1]);
    }
}

// ===== channel-split 8-row gather: 2 waves per node, each owns 64 channels.
// lane = (sub = lane>>3 row-slot, cidx = lane&7 16B-chunk of the 128B half).
// One dwordx4 instr fetches 8 neighbor rows (same cache-lines/instr as the
// quad layout but 2x rows, 1/2 VALU per row, 1/4 shfl per row, 2x waves).
// DEG_CAP=64 -> whole gather = <=8 load instrs, all issued in one burst.
// W2=true:  fuse conv2 GEMM. Half-waves exchange packed h via 512B LDS, then
//           split the 32 MFMAs 16/16 (ct in {4*half..4*half+3}); bitwise
//           identical fragments/pack/ks-order to the round-5 fused kernel.
// W2=false: conv2 aggregate + fused mean-pool numerator (batch sorted).
template <bool W2>
__device__ __forceinline__ void gather8_body(const uint4* __restrict__ tbq,
                                             const int* __restrict__ csr_src,
                                             const int* __restrict__ cnt,
                                             const float* __restrict__ bias,
                                             const unsigned short* __restrict__ Wb,
                                             unsigned short* __restrict__ tb2,
                                             const int* __restrict__ batch,
                                             float* __restrict__ psum) {
    const int tid = threadIdx.x;
    const int wid = tid >> 6;
    const int lane = tid & 63;
    const int nib = wid >> 1;        // node within block (0..1)
    const int half = wid & 1;        // channel half (0..1)
    const int sub = lane >> 3;       // row slot (0..7)
    const int cidx = lane & 7;       // 16B chunk within the 128B half-row
    const int v = blockIdx.x * 2 + nib;

    int lenc = cnt[v];
    const float dv = rsqrtf((float)(lenc + 1));
    int len = lenc > DEG_CAP ? DEG_CAP : lenc;

    int u_l = 0;
    float w_l = 0.f;
    if (lane < len) {
        u_l = csr_src[(v << 6) + lane];                       // coalesced 256B
        if (W2) w_l = rsqrtf((float)(cnt[u_l] + 1));          // scattered 4B, L2
    }

    const int nb = (len + 7) >> 3;   // 8-row bursts; nb <= 8 (wave-uniform)
    uint4 q[8];
    float w[8];
    #pragma unroll
    for (int k = 0; k < 8; ++k) {
        if (k < nb) {
            int ridx = k * 8 + sub;
            bool act = ridx < len;
            int ic = act ? ridx : 0;
            int u = __shfl(u_l, ic);
            float ws = W2 ? __shfl(w_l, ic) : 1.f;
            w[k] = act ? ws : 0.f;
            q[k] = tbq[(size_t)u * 16 + half * 8 + cidx];   // 8 rows / instr
        }
    }
    uint4 qs = tbq[(size_t)v * 16 + half * 8 + cidx];       // self row

    float x[8];
    #pragma unroll
    for (int t = 0; t < 8; ++t) x[t] = 0.f;
    #pragma unroll
    for (int k = 0; k < 8; ++k)
        if (k < nb) acc_row(x, q[k], w[k]);
    acc_row(x, qs, (sub == 0) ? (W2 ? dv : 1.f) : 0.f);     // self counted once

    // reduce across the 8 row-slots (lane bits 3,4,5)
    #pragma unroll
    for (int t = 0; t < 8; ++t) {
        x[t] += __shfl_xor(x[t], 8);
        x[t] += __shfl_xor(x[t], 16);
        x[t] += __shfl_xor(x[t], 32);
    }

    // bias for channels half*64 + cidx*8 .. +7
    const float4* b4 = (const float4*)bias;
    float4 b0 = b4[half * 16 + cidx * 2], b1v = b4[half * 16 + cidx * 2 + 1];
    float o[8];
    o[0] = fmaxf(fmaf(dv, x[0], b0.x), 0.f);
    o[1] = fmaxf(fmaf(dv, x[1], b0.y), 0.f);
    o[2] = fmaxf(fmaf(dv, x[2], b0.z), 0.f);
    o[3] = fmaxf(fmaf(dv, x[3], b0.w), 0.f);
    o[4] = fmaxf(fmaf(dv, x[4], b1v.x), 0.f);
    o[5] = fmaxf(fmaf(dv, x[5], b1v.y), 0.f);
    o[6] = fmaxf(fmaf(dv, x[6], b1v.z), 0.f);
    o[7] = fmaxf(fmaf(dv, x[7], b1v.w), 0.f);

    if constexpr (W2) {
        // pack h half to bf16 and exchange via LDS (chunk id = half*8+cidx)
        __shared__ uint4 shh[2][16];
        if (sub == 0) {
            uint4 pkv;
            pkv.x = pack_bf16(o[0], o[1]);
            pkv.y = pack_bf16(o[2], o[3]);
            pkv.z = pack_bf16(o[4], o[5]);
            pkv.w = pack_bf16(o[6], o[7]);
            shh[nib][half * 8 + cidx] = pkv;
        }
        __syncthreads();

        const int quad = lane >> 4;
        const int m = lane & 15;
        FragU af[4];
        #pragma unroll
        for (int ks = 0; ks < 4; ++ks) af[ks].u = shh[nib][ks * 4 + quad];

        f32x4 acc[4];
        #pragma unroll
        for (int j = 0; j < 4; ++j) acc[j] = (f32x4){0.f, 0.f, 0.f, 0.f};
        const uint4* Wq = (const uint4*)Wb;
        #pragma unroll
        for (int ks = 0; ks < 4; ++ks) {
            #pragma unroll
            for (int j = 0; j < 4; ++j) {
                FragU bfu;   // ct = half*4+j -> col n = m*8 + half*4 + j
                bfu.u = Wq[(ks << 9) + ((half * 4 + j) << 6) + lane];
                acc[j] = __builtin_amdgcn_mfma_f32_16x16x32_bf16(af[ks].s, bfu.s, acc[j], 0, 0, 0);
            }
        }
        if (quad == 0) {     // D row 0 = h @ W2; scale by dv, pack, 8B store
            uint2 ov;
            ov.x = pack_bf16(acc[0][0] * dv, acc[1][0] * dv);
            ov.y = pack_bf16(acc[2][0] * dv, acc[3][0] * dv);
            *(uint2*)(tb2 + (size_t)v * CH + m * 8 + half * 4) = ov;
        }
    } else {
        __shared__ float sh[2][128];
        __shared__ int sg[2];
        if (lane == 0 && half == 0) sg[nib] = batch[v];
        if (sub == 0) {
            float4* shp = (float4*)&sh[nib][half * 64 + cidx * 8];
            shp[0] = (float4){o[0], o[1], o[2], o[3]};
            shp[1] = (float4){o[4], o[5], o[6], o[7]};
        }
        __syncthreads();
        if (tid < 128) {
            int g0 = sg[0], g1 = sg[1];
            float v0 = sh[0][tid], v1 = sh[1][tid];
            if (g0 == g1) {
                atomicAdd(&psum[g0 * CH + tid], v0 + v1);
            } else {
                atomicAdd(&psum[g0 * CH + tid], v0);
                atomicAdd(&psum[g1 * CH + tid], v1);
            }
        }
    }
}

// FUSED conv1 aggregate + conv2 GEMM: tb -> tb2 (scaled bf16)
__global__ __launch_bounds__(256) void k_gather_w2(const unsigned* __restrict__ tb,
                                                   const int* __restrict__ csr_src,
                                                   const int* __restrict__ cnt,
                                                   const float* __restrict__ bias,
                                                   const unsigned short* __restrict__ Wb,
                                                   unsigned short* __restrict__ tb2) {
    gather8_body<true>((const uint4*)tb, csr_src, cnt, bias, Wb, tb2, nullptr, nullptr);
}

// conv2 aggregate (pre-scaled rows) + fused mean-pool numerator -> psum
__global__ __launch_bounds__(256) void k_gather_pool(const unsigned* __restrict__ tb,
                                                     const int* __restrict__ csr_src,
                                                     const int* __restrict__ cnt,
                                                     const float* __restrict__ bias,
                                                     const int* __restrict__ batch,
                                                     float* __restrict__ psum) {
    gather8_body<false>((const uint4*)tb, csr_src, cnt, bias, nullptr, nullptr, batch, psum);
}

// ================= classifier head (count via binary search) =================
__global__ __launch_bounds__(128) void k_classify(const float* __restrict__ psum,
                                                  const int* __restrict__ batch,
                                                  const float* __restrict__ Wc,
                                                  const float* __restrict__ bc,
                                                  float* __restrict__ out) {
    __shared__ float p[CH];
    __shared__ float sinv;
    int g = blockIdx.x;
    int tid = threadIdx.x;
    if (tid == 0) {
        int lo = 0, hi = N_NODES;
        while (lo < hi) { int mid = (lo + hi) >> 1; if (batch[mid] < g) lo = mid + 1; else hi = mid; }
        int start = lo;
        lo = 0; hi = N_NODES;
        while (lo < hi) { int mid = (lo + hi) >> 1; if (batch[mid] < g + 1) lo = mid + 1; else hi = mid; }
        sinv = 1.0f / fmaxf((float)(lo - start), 1.0f);
    }
    __syncthreads();
    p[tid] = psum[g * CH + tid] * sinv;
    __syncthreads();
    if (tid < NOUT) {
        float acc = bc[tid];
        #pragma unroll 4
        for (int k = 0; k < CH; ++k) acc += p[k] * Wc[k * NOUT + tid];
        out[g * NOUT + tid] = acc;
    }
}

extern "C" void kernel_launch(void* const* d_in, const int* in_sizes, int n_in,
                              void* d_out, int out_size, void* d_ws, size_t ws_size,
                              hipStream_t stream) {
    const float* x     = (const float*)d_in[0];
    const int*   ei    = (const int*)d_in[1];
    const int*   batch = (const int*)d_in[2];
    const float* W1    = (const float*)d_in[3];
    const float* b1    = (const float*)d_in[4];
    const float* W2    = (const float*)d_in[5];
    const float* b2    = (const float*)d_in[6];
    const float* Wc    = (const float*)d_in[7];
    const float* bc    = (const float*)d_in[8];
    float* out = (float*)d_out;

    const int* src = ei;
    const int* dst = ei + N_EDGES;

    int*            fill_pos = (int*)d_ws;                              // N (deg after fill)
    int*            csr_src  = fill_pos + N_NODES;                      // N*64
    unsigned short* wb1      = (unsigned short*)(csr_src + (size_t)N_NODES * DEG_CAP);
    unsigned short* wb2      = wb1 + CH * CH;
    unsigned short* tb       = wb2 + CH * CH;                           // N*128 bf16 (conv1 out)
    unsigned short* tb2      = tb + (size_t)N_NODES * CH;               // N*128 bf16 (conv2 pre-agg)
    float*          psum     = (float*)(tb2 + (size_t)N_NODES * CH);    // G*CH

    // K0: W convert + zero fill_pos + zero psum
    k_prep<<<198 + 64, 256, 0, stream>>>(W1, W2, wb1, wb2, fill_pos, psum);

    // K1: conv1 GEMM (unscaled tb) ∥ bucket CSR fill
    k_gemm_fill<<<GEMM_BLOCKS + FILL_BLOCKS, 256, 0, stream>>>(
        x, wb1, tb, src, dst, fill_pos, csr_src);

    // FUSED conv1 aggregate + conv2 GEMM: tb -> tb2 (scaled bf16)
    k_gather_w2<<<N_NODES / 2, 256, 0, stream>>>((unsigned*)tb, csr_src, fill_pos, b1,
                                                 wb2, tb2);

    // conv2 aggregate + fused mean-pool numerator
    k_gather_pool<<<N_NODES / 2, 256, 0, stream>>>((unsigned*)tb2, csr_src, fill_pos, b2,
                                                   batch, psum);

    // head
    k_classify<<<NUM_GRAPHS, 128, 0, stream>>>(psum, batch, Wc, bc, out);
}

// Round 7
// 256.971 us; speedup vs baseline: 1.2104x; 1.2104x over previous
//
#include <hip/hip_runtime.h>

#define N_NODES 50000
#define N_EDGES 800000
#define CH 128
#define NOUT 10
#define NUM_GRAPHS 128
#define GR 64                                              // rows per block
#define GEMM_BLOCKS ((N_NODES + GR - 1) / GR)              // 782
#define FILL_EPB 2048                                      // edges per fill block
#define FILL_BLOCKS ((N_EDGES + FILL_EPB - 1) / FILL_EPB)  // 391
#define DEG_CAP 64

typedef __attribute__((ext_vector_type(8))) short bf16x8;
typedef __attribute__((ext_vector_type(4))) float f32x4;

union FragU { uint4 u; bf16x8 s; };

__device__ __forceinline__ unsigned pack_bf16(float a, float b) {
    unsigned ua = __float_as_uint(a), ub = __float_as_uint(b);
    ua += 0x7fffu + ((ua >> 16) & 1u);
    ub += 0x7fffu + ((ub >> 16) & 1u);
    return (ua >> 16) | (ub & 0xffff0000u);
}

__device__ __forceinline__ unsigned short cvt_bf16(float v) {
    unsigned u = __float_as_uint(v);
    u += 0x7fffu + ((u >> 16) & 1u);
    return (unsigned short)(u >> 16);
}

// ===== K0: W pre-convert + zero fill_pos + zero psum =====
__global__ __launch_bounds__(256) void k_prep(const float* __restrict__ W1,
                                              const float* __restrict__ W2,
                                              unsigned short* __restrict__ Wb1,
                                              unsigned short* __restrict__ Wb2,
                                              int* __restrict__ fill_pos,
                                              float* __restrict__ psum) {
    if (blockIdx.x < 2) {
        const float* W = blockIdx.x ? W2 : W1;
        unsigned short* Wb = blockIdx.x ? Wb2 : Wb1;
        for (int i = threadIdx.x; i < CH * CH; i += 256) {
            int k = i >> 7, n = i & 127;
            Wb[((((k >> 3) << 7) + n) << 3) + (k & 7)] = cvt_bf16(W[i]);
        }
    } else if (blockIdx.x < 198) {
        int idx = (blockIdx.x - 2) * 256 + threadIdx.x;
        if (idx < N_NODES) fill_pos[idx] = 0;
    } else {
        psum[(blockIdx.x - 198) * 256 + threadIdx.x] = 0.f;
    }
}

// ===== MFMA GEMM body; SCALE folds rsqrt(cnt+1) into the epilogue ==========
// 256 thr = 4 waves; wave w: rows w*16..+15, all 128 cols. No LDS/barriers.
// A: fp32 global -> bf16 in-register; ALL 8 float4 A-loads hoisted up front.
template <bool SCALE>
__device__ __forceinline__ void gemm_body9(const float* __restrict__ X,
                                           const unsigned short* __restrict__ Wb,
                                           unsigned short* __restrict__ Yb,
                                           const int* __restrict__ cnt,
                                           int bid) {
    const int tid = threadIdx.x;
    const int w = tid >> 6;
    const int lane = tid & 63;
    const int m = lane & 15;
    const int quad = lane >> 4;
    const int row0 = bid * GR + w * 16;

    int row_a = row0 + m;
    if (row_a > N_NODES - 1) row_a = N_NODES - 1;
    const float4* Xr = (const float4*)(X + (size_t)row_a * CH) + quad * 2;

    float4 a[8];
    #pragma unroll
    for (int ks = 0; ks < 4; ++ks) {
        a[ks * 2]     = Xr[ks * 8];
        a[ks * 2 + 1] = Xr[ks * 8 + 1];
    }

    f32x4 acc[8];
    #pragma unroll
    for (int ct = 0; ct < 8; ++ct) acc[ct] = (f32x4){0.f, 0.f, 0.f, 0.f};

    const uint4* Wq = (const uint4*)Wb;
    #pragma unroll
    for (int ks = 0; ks < 4; ++ks) {
        FragU af;
        af.u.x = pack_bf16(a[ks * 2].x, a[ks * 2].y);
        af.u.y = pack_bf16(a[ks * 2].z, a[ks * 2].w);
        af.u.z = pack_bf16(a[ks * 2 + 1].x, a[ks * 2 + 1].y);
        af.u.w = pack_bf16(a[ks * 2 + 1].z, a[ks * 2 + 1].w);
        const int kg = ks * 4 + quad;
        #pragma unroll
        for (int ct = 0; ct < 8; ++ct) {
            FragU bfu;
            bfu.u = Wq[kg * 128 + ct * 16 + m];
            acc[ct] = __builtin_amdgcn_mfma_f32_16x16x32_bf16(af.s, bfu.s, acc[ct], 0, 0, 0);
        }
    }

    #pragma unroll
    for (int r = 0; r < 4; ++r) {
        int row = row0 + quad * 4 + r;
        if (row < N_NODES) {
            float dv = SCALE ? rsqrtf((float)(cnt[row] + 1)) : 1.0f;
            unsigned short* yrow = Yb + (size_t)row * CH + m;
            #pragma unroll
            for (int ct = 0; ct < 8; ++ct)
                yrow[ct * 16] = cvt_bf16(SCALE ? acc[ct][r] * dv : acc[ct][r]);
        }
    }
}

// ===== K1: conv1 GEMM ∥ SINGLE-PASS fill (no range bucketing: device atomics
// are LLC-side regardless of which XCD issues them, so the 8x replicated scan
// bought nothing — each edge is now touched exactly once).
__global__ __launch_bounds__(256) void k_gemm_fill(const float* __restrict__ X,
                                                   const unsigned short* __restrict__ Wb,
                                                   unsigned short* __restrict__ Yb,
                                                   const int* __restrict__ src,
                                                   const int* __restrict__ dst,
                                                   int* __restrict__ fill_pos,
                                                   int* __restrict__ csr_src) {
    if (blockIdx.x < GEMM_BLOCKS) {
        gemm_body9<false>(X, Wb, Yb, nullptr, blockIdx.x);
    } else {
        const int b = blockIdx.x - GEMM_BLOCKS;
        const int base = b * FILL_EPB;
        int4 d4[2], s4[2];
        #pragma unroll
        for (int i = 0; i < 2; ++i) {
            int e = base + ((int)threadIdx.x + i * 256) * 4;
            if (e < N_EDGES) {
                d4[i] = *(const int4*)(dst + e);
                s4[i] = *(const int4*)(src + e);
            }
        }
        #pragma unroll
        for (int i = 0; i < 2; ++i) {
            int e = base + ((int)threadIdx.x + i * 256) * 4;
            if (e < N_EDGES) {
                #pragma unroll
                for (int k = 0; k < 4; ++k) {
                    int d = (&d4[i].x)[k];
                    int slot = atomicAdd(&fill_pos[d], 1);
                    if (slot < DEG_CAP) csr_src[(d << 6) + slot] = (&s4[i].x)[k];
                }
            }
        }
    }
}

// conv2 GEMM (dinv folded from cnt): hbuf fp32 -> tb scaled bf16
__global__ __launch_bounds__(256) void k_gemm9b(const float* __restrict__ X,
                                                const unsigned short* __restrict__ Wb,
                                                unsigned short* __restrict__ Yb,
                                                const int* __restrict__ cnt) {
    gemm_body9<true>(X, Wb, Yb, cnt, blockIdx.x);
}

// ===== quad-gather: wave = 1 node; 4 quads fetch 4 neighbor rows per dwordx4.
// lane(sub=lane>>4, cidx=lane&15) reads 16B = channels cidx*8..+7 of one row.
// 8 f32 accumulators per lane; cross-quad shfl_xor(16/32) reduce at the end.
// HAS_W: per-neighbor weight rsqrt(cnt[u]+1) (conv1, unscaled rows).
// POOL:  fuse segmented mean-pool numerator (batch sorted) via LDS + atomics.
template <bool HAS_W, bool POOL>
__device__ __forceinline__ void gather_body(const unsigned* __restrict__ tb,
                                            const int* __restrict__ csr_src,
                                            const int* __restrict__ cnt,
                                            const float* __restrict__ bias,
                                            float* __restrict__ h,
                                            const int* __restrict__ batch,
                                            float* __restrict__ psum) {
    const int wid = threadIdx.x >> 6;
    const int lane = threadIdx.x & 63;
    const int sub = lane >> 4;       // quad id: which row of a 4-row fetch group
    const int cidx = lane & 15;      // which 16B chunk of the 256B row
    const int v = blockIdx.x * 4 + wid;     // 12500 * 4 = 50000

    int lenc = cnt[v];
    const float dv = rsqrtf((float)(lenc + 1));
    int len = lenc > DEG_CAP ? DEG_CAP : lenc;

    int u_l = 0;
    float w_l = 0.f;
    if (lane < len) {
        u_l = csr_src[(v << 6) + lane];                       // coalesced
        if (HAS_W) w_l = rsqrtf((float)(cnt[u_l] + 1));       // scattered 4B, L2
    }

    const uint4* tbq = (const uint4*)tb;
    float x[8];
    #pragma unroll
    for (int t = 0; t < 8; ++t) x[t] = 0.f;

    int j = 0;
    for (; j + 8 <= len; j += 8) {           // 2 groups (8 rows) per iter
        int i0 = j + sub, i1 = j + 4 + sub;
        int ua = __shfl(u_l, i0);
        int ub = __shfl(u_l, i1);
        float wa = HAS_W ? __shfl(w_l, i0) : 1.f;
        float wb = HAS_W ? __shfl(w_l, i1) : 1.f;
        uint4 qa = tbq[(size_t)ua * 16 + cidx];   // 1 instr = 4 rows x 256B
        uint4 qb = tbq[(size_t)ub * 16 + cidx];
        #pragma unroll
        for (int t = 0; t < 4; ++t) {
            unsigned ra = ((const unsigned*)&qa)[t];
            x[2 * t]     = fmaf(wa, __uint_as_float(ra << 16), x[2 * t]);
            x[2 * t + 1] = fmaf(wa, __uint_as_float(ra & 0xffff0000u), x[2 * t + 1]);
        }
        #pragma unroll
        for (int t = 0; t < 4; ++t) {
            unsigned rb = ((const unsigned*)&qb)[t];
            x[2 * t]     = fmaf(wb, __uint_as_float(rb << 16), x[2 * t]);
            x[2 * t + 1] = fmaf(wb, __uint_as_float(rb & 0xffff0000u), x[2 * t + 1]);
        }
    }
    for (; j < len; j += 4) {                // predicated tail group
        int idx = j + sub;
        bool act = idx < len;
        int idx_c = act ? idx : 0;
        int u = __shfl(u_l, idx_c);
        float w;
        if (HAS_W) { float ws = __shfl(w_l, idx_c); w = act ? ws : 0.f; }
        else       { w = act ? 1.f : 0.f; }
        uint4 q = tbq[(size_t)u * 16 + cidx];
        #pragma unroll
        for (int t = 0; t < 4; ++t) {
            unsigned r = ((const unsigned*)&q)[t];
            x[2 * t]     = fmaf(w, __uint_as_float(r << 16), x[2 * t]);
            x[2 * t + 1] = fmaf(w, __uint_as_float(r & 0xffff0000u), x[2 * t + 1]);
        }
    }
    {   // self term: only quad 0 accumulates (weight dv for conv1, 1 for conv2)
        uint4 q = tbq[(size_t)v * 16 + cidx];
        float w = (sub == 0) ? (HAS_W ? dv : 1.f) : 0.f;
        #pragma unroll
        for (int t = 0; t < 4; ++t) {
            unsigned r = ((const unsigned*)&q)[t];
            x[2 * t]     = fmaf(w, __uint_as_float(r << 16), x[2 * t]);
            x[2 * t + 1] = fmaf(w, __uint_as_float(r & 0xffff0000u), x[2 * t + 1]);
        }
    }

    // cross-quad reduce: lanes {l, l^16, l^32, l^48} hold partials of same channels
    #pragma unroll
    for (int t = 0; t < 8; ++t) {
        x[t] += __shfl_xor(x[t], 16);
        x[t] += __shfl_xor(x[t], 32);
    }

    const float4* b4 = (const float4*)bias;
    float4 b0 = b4[cidx * 2], b1 = b4[cidx * 2 + 1];
    float4 o0, o1;
    o0.x = fmaxf(fmaf(dv, x[0], b0.x), 0.f);
    o0.y = fmaxf(fmaf(dv, x[1], b0.y), 0.f);
    o0.z = fmaxf(fmaf(dv, x[2], b0.z), 0.f);
    o0.w = fmaxf(fmaf(dv, x[3], b0.w), 0.f);
    o1.x = fmaxf(fmaf(dv, x[4], b1.x), 0.f);
    o1.y = fmaxf(fmaf(dv, x[5], b1.y), 0.f);
    o1.z = fmaxf(fmaf(dv, x[6], b1.z), 0.f);
    o1.w = fmaxf(fmaf(dv, x[7], b1.w), 0.f);

    if (POOL) {
        __shared__ float sh[4][128];
        __shared__ int sg[4];
        if (lane == 0) sg[wid] = batch[v];
        if (sub == 0) {
            *(float4*)&sh[wid][cidx * 8]     = o0;
            *(float4*)&sh[wid][cidx * 8 + 4] = o1;
        }
        __syncthreads();
        const int tid = threadIdx.x;
        if (tid < 128) {
            int g0 = sg[0], g1 = sg[1], g2 = sg[2], g3 = sg[3];
            float v0 = sh[0][tid], v1 = sh[1][tid], v2 = sh[2][tid], v3 = sh[3][tid];
            if (g0 == g3) {
                atomicAdd(&psum[g0 * CH + tid], v0 + v1 + v2 + v3);
            } else {          // graph boundary inside block (<=127 blocks total)
                if (g0 == g1) v1 += v0; else atomicAdd(&psum[g0 * CH + tid], v0);
                if (g1 == g2) v2 += v1; else atomicAdd(&psum[g1 * CH + tid], v1);
                if (g2 == g3) v3 += v2; else atomicAdd(&psum[g2 * CH + tid], v2);
                atomicAdd(&psum[g3 * CH + tid], v3);
            }
        }
    } else {
        if (sub == 0) {
            float4* hq = (float4*)(h + (size_t)v * CH);
            hq[cidx * 2]     = o0;
            hq[cidx * 2 + 1] = o1;
        }
    }
}

// conv1 aggregate: inline per-neighbor dinv[u], unscaled tb rows -> hbuf fp32
__global__ __launch_bounds__(256) void k_gather_hw(const unsigned* __restrict__ tb,
                                                   const int* __restrict__ csr_src,
                                                   const int* __restrict__ cnt,
                                                   const float* __restrict__ b,
                                                   float* __restrict__ h) {
    gather_body<true, false>(tb, csr_src, cnt, b, h, nullptr, nullptr);
}

// conv2 aggregate (pre-scaled rows) + fused mean-pool numerator -> psum
__global__ __launch_bounds__(256) void k_gather_pool(const unsigned* __restrict__ tb,
                                                     const int* __restrict__ csr_src,
                                                     const int* __restrict__ cnt,
                                                     const float* __restrict__ b,
                                                     const int* __restrict__ batch,
                                                     float* __restrict__ psum) {
    gather_body<false, true>(tb, csr_src, cnt, b, nullptr, batch, psum);
}

// ================= classifier head (count via binary search) =================
__global__ __launch_bounds__(128) void k_classify(const float* __restrict__ psum,
                                                  const int* __restrict__ batch,
                                                  const float* __restrict__ Wc,
                                                  const float* __restrict__ bc,
                                                  float* __restrict__ out) {
    __shared__ float p[CH];
    __shared__ float sinv;
    int g = blockIdx.x;
    int tid = threadIdx.x;
    if (tid == 0) {
        int lo = 0, hi = N_NODES;
        while (lo < hi) { int mid = (lo + hi) >> 1; if (batch[mid] < g) lo = mid + 1; else hi = mid; }
        int start = lo;
        lo = 0; hi = N_NODES;
        while (lo < hi) { int mid = (lo + hi) >> 1; if (batch[mid] < g + 1) lo = mid + 1; else hi = mid; }
        sinv = 1.0f / fmaxf((float)(lo - start), 1.0f);
    }
    __syncthreads();
    p[tid] = psum[g * CH + tid] * sinv;
    __syncthreads();
    if (tid < NOUT) {
        float acc = bc[tid];
        #pragma unroll 4
        for (int k = 0; k < CH; ++k) acc += p[k] * Wc[k * NOUT + tid];
        out[g * NOUT + tid] = acc;
    }
}

extern "C" void kernel_launch(void* const* d_in, const int* in_sizes, int n_in,
                              void* d_out, int out_size, void* d_ws, size_t ws_size,
                              hipStream_t stream) {
    const float* x     = (const float*)d_in[0];
    const int*   ei    = (const int*)d_in[1];
    const int*   batch = (const int*)d_in[2];
    const float* W1    = (const float*)d_in[3];
    const float* b1    = (const float*)d_in[4];
    const float* W2    = (const float*)d_in[5];
    const float* b2    = (const float*)d_in[6];
    const float* Wc    = (const float*)d_in[7];
    const float* bc    = (const float*)d_in[8];
    float* out = (float*)d_out;

    const int* src = ei;
    const int* dst = ei + N_EDGES;

    int*            fill_pos = (int*)d_ws;                              // N (deg after fill)
    int*            csr_src  = fill_pos + N_NODES;                      // N*64
    unsigned short* wb1      = (unsigned short*)(csr_src + (size_t)N_NODES * DEG_CAP);
    unsigned short* wb2      = wb1 + CH * CH;
    unsigned short* tb       = wb2 + CH * CH;                           // N*128 bf16
    float*          hbuf     = (float*)(tb + (size_t)N_NODES * CH);     // N*CH fp32
    float*          psum     = hbuf + (size_t)N_NODES * CH;             // G*CH

    // K0: W convert + zero fill_pos + zero psum
    k_prep<<<198 + 64, 256, 0, stream>>>(W1, W2, wb1, wb2, fill_pos, psum);

    // K1: conv1 GEMM (unscaled tb) ∥ single-pass CSR fill
    k_gemm_fill<<<GEMM_BLOCKS + FILL_BLOCKS, 256, 0, stream>>>(
        x, wb1, tb, src, dst, fill_pos, csr_src);

    // conv1 aggregate: quad-gather, inline dinv[u]
    k_gather_hw<<<N_NODES / 4, 256, 0, stream>>>((unsigned*)tb, csr_src, fill_pos, b1, hbuf);

    // conv2 GEMM (folds dinv from counts): hbuf -> tb (scaled)
    k_gemm9b<<<GEMM_BLOCKS, 256, 0, stream>>>(hbuf, wb2, tb, fill_pos);

    // conv2 aggregate + fused mean-pool numerator
    k_gather_pool<<<N_NODES / 4, 256, 0, stream>>>((unsigned*)tb, csr_src, fill_pos, b2,
                                                   batch, psum);

    // head
    k_classify<<<NUM_GRAPHS, 128, 0, stream>>>(psum, batch, Wc, bc, out);
}